// Round 3
// baseline (1047.129 us; speedup 1.0000x reference)
//
#include <hip/hip_runtime.h>
#include <hip/hip_bf16.h>
#include <hip/hip_cooperative_groups.h>
#include <math.h>

namespace cg = cooperative_groups;

#define NB 2        // batch
#define NC 64       // channels
#define ND 8        // head dim (C/8)
#define NN 4096     // tokens (T*W*H)
#define NM 256      // landmarks
#define NL 16       // N/M
#define SCALE 0.35355339059327373f  // 1/sqrt(8)

typedef __attribute__((ext_vector_type(4))) float f32x4;
typedef __attribute__((ext_vector_type(8))) short bf16x8;
typedef __attribute__((ext_vector_type(4))) int int4v;

__device__ inline ushort f2bf(float f) {
  __hip_bfloat16 h = __float2bfloat16(f);
  return *reinterpret_cast<ushort*>(&h);
}
__device__ inline float bf2f(ushort u) {
  return __uint_as_float(((unsigned int)u) << 16);
}

// ---------------- qkv projection, output-row parallel ----------------
// grid (80, NN/1024, NB); block 256; each thread 4 tokens (float4)
__global__ __launch_bounds__(256) void qkv2_kernel(
    const float* __restrict__ x,
    const float* __restrict__ wq, const float* __restrict__ bq,
    const float* __restrict__ wk, const float* __restrict__ bk,
    const float* __restrict__ wv, const float* __restrict__ bv,
    float* __restrict__ q, float* __restrict__ k, float* __restrict__ v) {
  __shared__ float ws[NC];
  int o = blockIdx.x;            // 0..79: 0-7 q, 8-15 k, 16-79 v
  int b = blockIdx.z;
  int n0 = blockIdx.y * 1024;
  int t = threadIdx.x;
  const float* wrow;
  float bias;
  if (o < ND)            { wrow = wq + (size_t)o * NC;            bias = bq[o]; }
  else if (o < 2 * ND)   { wrow = wk + (size_t)(o - ND) * NC;     bias = bk[o - ND]; }
  else                   { wrow = wv + (size_t)(o - 2 * ND) * NC; bias = bv[o - 2 * ND]; }
  if (t < NC) ws[t] = wrow[t];
  __syncthreads();
  int n = n0 + t * 4;
  float4 acc = {bias, bias, bias, bias};
  #pragma unroll
  for (int c = 0; c < NC; ++c) {
    float wc = ws[c];
    float4 xv = *(const float4*)(x + ((size_t)b * NC + c) * NN + n);
    acc.x += wc * xv.x; acc.y += wc * xv.y; acc.z += wc * xv.z; acc.w += wc * xv.w;
  }
  if (o < ND) {
    float* qp = q + ((size_t)b * NN + n) * ND + o;
    qp[0] = acc.x; qp[8] = acc.y; qp[16] = acc.z; qp[24] = acc.w;
  } else if (o < 2 * ND) {
    float* kp = k + ((size_t)b * NN + n) * ND + (o - ND);
    kp[0] = acc.x; kp[8] = acc.y; kp[16] = acc.z; kp[24] = acc.w;
  } else {
    *(float4*)(v + ((size_t)b * NC + (o - 2 * ND)) * NN + n) = acc;
  }
}

// ---------------- landmarks ----------------
__global__ void landmark_kernel(const float* __restrict__ q, const float* __restrict__ k,
                                float* __restrict__ ql, float* __restrict__ kl) {
  int idx = blockIdx.x * 256 + threadIdx.x;
  int b = idx / (NM * ND), r = idx % (NM * ND), i = r / ND, o = r % ND;
  float sq = 0.f, sk = 0.f;
  for (int l = 0; l < NL; ++l) {
    size_t base = ((size_t)b * NN + i * NL + l) * ND + o;
    sq += q[base]; sk += k[base];
  }
  ql[idx] = sq * (1.0f / NL);
  kl[idx] = sk * (1.0f / NL);
}

// ---------------- softmax rows vs landmarks (k1 and k2) ----------------
__global__ __launch_bounds__(256) void scores_softmax_m(
    const float* __restrict__ Q, int R, const float* __restrict__ KL,
    float* __restrict__ out) {
  __shared__ float skl[NM][9];
  int b = blockIdx.y;
  int t = threadIdx.x;
  for (int i = t; i < NM * ND; i += 256) skl[i >> 3][i & 7] = KL[(size_t)b * NM * ND + i];
  __syncthreads();
  int wave = t >> 6, lane = t & 63;
  int r = blockIdx.x * 4 + wave;
  const float* qrow = Q + ((size_t)b * R + r) * ND;
  float qr[ND];
  #pragma unroll
  for (int dd = 0; dd < ND; ++dd) qr[dd] = qrow[dd];
  float sc[4];
  float lmax = -1e30f;
  #pragma unroll
  for (int s = 0; s < 4; ++s) {
    int j = lane + 64 * s;
    float a = 0.f;
    #pragma unroll
    for (int dd = 0; dd < ND; ++dd) a += qr[dd] * skl[j][dd];
    sc[s] = a * SCALE;
    lmax = fmaxf(lmax, sc[s]);
  }
  for (int off = 32; off; off >>= 1) lmax = fmaxf(lmax, __shfl_xor(lmax, off));
  float lsum = 0.f;
  #pragma unroll
  for (int s = 0; s < 4; ++s) { sc[s] = expf(sc[s] - lmax); lsum += sc[s]; }
  for (int off = 32; off; off >>= 1) lsum += __shfl_xor(lsum, off);
  float inv = 1.0f / lsum;
  #pragma unroll
  for (int s = 0; s < 4; ++s) out[((size_t)b * R + r) * NM + lane + 64 * s] = sc[s] * inv;
}

// ---------------- k3 softmax ----------------
__global__ __launch_bounds__(256) void scores_softmax_n(
    const float* __restrict__ QL, const float* __restrict__ Kt,
    float* __restrict__ out) {
  __shared__ float wred[4], wsum[4];
  int b = blockIdx.y, i = blockIdx.x;
  int t = threadIdx.x;
  float qr[ND];
  #pragma unroll
  for (int dd = 0; dd < ND; ++dd) qr[dd] = QL[((size_t)b * NM + i) * ND + dd];
  float sc[16];
  float lmax = -1e30f;
  #pragma unroll
  for (int s = 0; s < 16; ++s) {
    int n = t + 256 * s;
    const float* kp = Kt + ((size_t)b * NN + n) * ND;
    float a = 0.f;
    #pragma unroll
    for (int dd = 0; dd < ND; ++dd) a += qr[dd] * kp[dd];
    sc[s] = a * SCALE;
    lmax = fmaxf(lmax, sc[s]);
  }
  for (int off = 32; off; off >>= 1) lmax = fmaxf(lmax, __shfl_xor(lmax, off));
  if ((t & 63) == 0) wred[t >> 6] = lmax;
  __syncthreads();
  lmax = fmaxf(fmaxf(wred[0], wred[1]), fmaxf(wred[2], wred[3]));
  float lsum = 0.f;
  #pragma unroll
  for (int s = 0; s < 16; ++s) { sc[s] = expf(sc[s] - lmax); lsum += sc[s]; }
  for (int off = 32; off; off >>= 1) lsum += __shfl_xor(lsum, off);
  if ((t & 63) == 0) wsum[t >> 6] = lsum;
  __syncthreads();
  lsum = wsum[0] + wsum[1] + wsum[2] + wsum[3];
  float inv = 1.0f / lsum;
  #pragma unroll
  for (int s = 0; s < 16; ++s) out[((size_t)b * NM + i) * NN + t + 256 * s] = sc[s] * inv;
}

// ---------------- cooperative Newton-Schulz: denom + vinit + 6x4 GEMM phases ----------------
// out = s_a*A + s_ab*(A @ Bm) for this block's 32x32 tile; A,Bm,out batch-local [256][256]
__device__ __forceinline__ void tile_gemm32(
    const float* __restrict__ Ab, const float* __restrict__ Bb,
    float* __restrict__ outb, int bi, int bj, float s_a, float s_ab, int t,
    float (*As)[33], float (*Bs)[36]) {
  int lr = t >> 3, lc = (t & 7) * 4;
  int tx = t & 15, ty = t >> 4;
  float acc[2][2] = {};
  for (int k0 = 0; k0 < NM; k0 += 32) {
    float4 av = *(const float4*)(Ab + (size_t)(bi + lr) * NM + k0 + lc);
    float4 bv = *(const float4*)(Bb + (size_t)(k0 + lr) * NM + bj + lc);
    As[lc + 0][lr] = av.x; As[lc + 1][lr] = av.y;   // transposed: As[k][row]
    As[lc + 2][lr] = av.z; As[lc + 3][lr] = av.w;
    *(float4*)&Bs[lr][lc] = bv;                      // Bs[k][col]
    __syncthreads();
    #pragma unroll
    for (int kk = 0; kk < 32; ++kk) {
      float2 a2 = *(const float2*)&As[kk][ty * 2];
      float2 b2 = *(const float2*)&Bs[kk][tx * 2];
      acc[0][0] += a2.x * b2.x; acc[0][1] += a2.x * b2.y;
      acc[1][0] += a2.y * b2.x; acc[1][1] += a2.y * b2.y;
    }
    __syncthreads();
  }
  #pragma unroll
  for (int i = 0; i < 2; ++i) {
    size_t o = (size_t)(bi + ty * 2 + i) * NM + bj + tx * 2;
    float2 r;
    r.x = s_ab * acc[i][0]; r.y = s_ab * acc[i][1];
    if (s_a != 0.0f) { r.x += s_a * Ab[o]; r.y += s_a * Ab[o + 1]; }
    *(float2*)(outb + o) = r;
  }
}

__global__ __launch_bounds__(256) void ns_kernel(
    const float* __restrict__ k2, float* Va, float* Vb, float* Zb,
    float* T1, float* T2, float* denw) {
  cg::grid_group grid = cg::this_grid();
  __shared__ float As[32][33];
  __shared__ float Bs[32][36];
  int t = threadIdx.x;
  int bid = blockIdx.x;            // 0..127
  int b = bid >> 6;
  int tile = bid & 63;
  int bi = (tile >> 3) * 32, bj = (tile & 7) * 32;
  const float* k2b = k2 + (size_t)b * NM * NM;

  // ---- phase: denom (block 0 only) ----
  if (bid == 0) {
    float mc = -1e30f, mr = -1e30f;
    for (int bb = 0; bb < NB; ++bb) {
      float cs = 0.f, rs = 0.f;
      for (int i = 0; i < NM; ++i) {
        cs += k2[((size_t)bb * NM + i) * NM + t];
        rs += k2[((size_t)bb * NM + t) * NM + i];
      }
      mc = fmaxf(mc, cs); mr = fmaxf(mr, rs);
    }
    float* redc = &As[0][0];
    float* redr = &Bs[0][0];
    redc[t] = mc; redr[t] = mr;
    __syncthreads();
    for (int off = 128; off; off >>= 1) {
      if (t < off) {
        redc[t] = fmaxf(redc[t], redc[t + off]);
        redr[t] = fmaxf(redr[t], redr[t + off]);
      }
      __syncthreads();
    }
    if (t == 0) { denw[0] = 1.0f / (redc[0] * redr[0]); __threadfence(); }
    __syncthreads();
  }
  grid.sync();

  // ---- phase: V0 = k2^T * invdenom ----
  size_t boff = (size_t)b * NM * NM;
  float* VaB = Va + boff; float* VbB = Vb + boff;
  float* ZbB = Zb + boff; float* T1B = T1 + boff; float* T2B = T2 + boff;
  {
    float dval = denw[0];
    int r = t >> 3, c0 = (t & 7) * 4;
    #pragma unroll
    for (int j = 0; j < 4; ++j)
      VaB[(size_t)(bi + r) * NM + bj + c0 + j] =
          k2b[(size_t)(bj + c0 + j) * NM + bi + r] * dval;
  }
  grid.sync();

  // ---- 6 Newton-Schulz iterations, 4 GEMM phases each ----
  float* Vc = VaB; float* Vn = VbB;
  for (int it = 0; it < 6; ++it) {
    tile_gemm32(k2b, Vc, ZbB, bi, bj, 0.f, 1.f, t, As, Bs);    grid.sync(); // Z = K@V
    tile_gemm32(ZbB, ZbB, T1B, bi, bj, 7.f, -1.f, t, As, Bs);  grid.sync(); // T1 = 7Z - Z@Z
    tile_gemm32(ZbB, T1B, T2B, bi, bj, 15.f, -1.f, t, As, Bs); grid.sync(); // T2 = 15Z - Z@T1
    tile_gemm32(Vc, T2B, Vn, bi, bj, 3.25f, -0.25f, t, As, Bs);             // V' = 3.25V - .25V@T2
    float* tmp = Vc; Vc = Vn; Vn = tmp;
    if (it < 5) grid.sync();
  }
  // final V lands in Va
}

// ---------------- A = k1 @ Vinv, bf16 output ----------------
__global__ __launch_bounds__(256) void gemm_a_kernel(
    const float* __restrict__ A, const float* __restrict__ Bm,
    ushort* __restrict__ obf) {
  int b = blockIdx.z;
  int bi = blockIdx.y * 64, bj = blockIdx.x * 64;
  __shared__ float As[16][68];
  __shared__ float Bs[16][72];
  int t = threadIdx.x;
  int tx = t & 15, ty = t >> 4;
  const float* Ab = A + (size_t)b * NN * NM;
  const float* Bb = Bm + (size_t)b * NM * NM;
  float acc[4][4] = {};
  int lrow = t >> 2, lkc = (t & 3) << 2;
  int lkr = t >> 4, lc4 = (t & 15) << 2;
  for (int k0 = 0; k0 < NM; k0 += 16) {
    float4 av = *(const float4*)(Ab + (size_t)(bi + lrow) * NM + k0 + lkc);
    float4 bv = *(const float4*)(Bb + (size_t)(k0 + lkr) * NM + bj + lc4);
    As[lkc + 0][lrow] = av.x;
    As[lkc + 1][lrow] = av.y;
    As[lkc + 2][lrow] = av.z;
    As[lkc + 3][lrow] = av.w;
    *(float4*)&Bs[lkr][lc4] = bv;
    __syncthreads();
    #pragma unroll
    for (int kk = 0; kk < 16; ++kk) {
      float4 a4 = *(const float4*)&As[kk][ty << 2];
      float4 b4 = *(const float4*)&Bs[kk][tx << 2];
      float av_[4] = {a4.x, a4.y, a4.z, a4.w};
      float bv_[4] = {b4.x, b4.y, b4.z, b4.w};
      #pragma unroll
      for (int i = 0; i < 4; ++i)
        #pragma unroll
        for (int j = 0; j < 4; ++j) acc[i][j] += av_[i] * bv_[j];
    }
    __syncthreads();
  }
  #pragma unroll
  for (int i = 0; i < 4; ++i) {
    size_t o = ((size_t)b * NN + bi + (ty << 2) + i) * NM + bj + (tx << 2);
    ushort4 u;
    u.x = f2bf(acc[i][0]); u.y = f2bf(acc[i][1]);
    u.z = f2bf(acc[i][2]); u.w = f2bf(acc[i][3]);
    *(ushort4*)(obf + o) = u;
  }
}

// ---------------- k3: [B][NM][NN] fp32 -> k3t: [B][NN][NM] bf16 ----------------
__global__ __launch_bounds__(256) void cvt_t_kernel(const float* __restrict__ k3,
                                                    ushort* __restrict__ k3t) {
  int b = blockIdx.z;
  int n0 = blockIdx.x * 32, m0 = blockIdx.y * 32;
  __shared__ float tile[32][33];
  int t = threadIdx.x;
  int r = t >> 3, c4 = (t & 7) * 4;
  float4 v = *(const float4*)(k3 + ((size_t)b * NM + m0 + r) * NN + n0 + c4);
  tile[c4][r] = v.x; tile[c4 + 1][r] = v.y; tile[c4 + 2][r] = v.z; tile[c4 + 3][r] = v.w;
  __syncthreads();
  ushort4 u;
  u.x = f2bf(tile[r][c4]);     u.y = f2bf(tile[r][c4 + 1]);
  u.z = f2bf(tile[r][c4 + 2]); u.w = f2bf(tile[r][c4 + 3]);
  *(ushort4*)(k3t + ((size_t)b * NN + n0 + r) * NM + m0 + c4) = u;
}

// ---------------- attn = A @ k3 via bf16 MFMA, 128x128 tile ----------------
__global__ __launch_bounds__(256) void gemm_attn_mfma(
    const ushort* __restrict__ Abf, const ushort* __restrict__ K3T,
    float* __restrict__ attn) {
  int b = blockIdx.z;
  int bi = blockIdx.y * 128, bj = blockIdx.x * 128;
  __shared__ ushort As[128 * 64];
  __shared__ ushort Bs[128 * 64];
  int t = threadIdx.x;
  int wave = t >> 6, lane = t & 63;
  int wr = wave >> 1, wc = wave & 1;
  const ushort* Ab = Abf + (size_t)b * NN * NM;
  const ushort* Bb = K3T + (size_t)b * NN * NM;
  f32x4 acc[4][4] = {};
  int srow = t >> 1;
  int sch0 = (t & 1) * 4;
  for (int k0 = 0; k0 < NM; k0 += 64) {
    #pragma unroll
    for (int cc = 0; cc < 4; ++cc) {
      int ch = sch0 + cc;
      int4v a = *(const int4v*)(Ab + (size_t)(bi + srow) * NM + k0 + ch * 8);
      int4v bv = *(const int4v*)(Bb + (size_t)(bj + srow) * NM + k0 + ch * 8);
      int sw = (ch * 16) ^ ((srow & 7) << 4);
      *(int4v*)((char*)As + srow * 128 + sw) = a;
      *(int4v*)((char*)Bs + srow * 128 + sw) = bv;
    }
    __syncthreads();
    #pragma unroll
    for (int kk = 0; kk < 2; ++kk) {
      int koff = kk * 64 + (lane >> 4) * 16;
      bf16x8 af[4], bfv[4];
      #pragma unroll
      for (int mi = 0; mi < 4; ++mi) {
        int row = wr * 64 + mi * 16 + (lane & 15);
        af[mi] = *(const bf16x8*)((const char*)As + row * 128 + (koff ^ ((row & 7) << 4)));
      }
      #pragma unroll
      for (int nj = 0; nj < 4; ++nj) {
        int row = wc * 64 + nj * 16 + (lane & 15);
        bfv[nj] = *(const bf16x8*)((const char*)Bs + row * 128 + (koff ^ ((row & 7) << 4)));
      }
      #pragma unroll
      for (int mi = 0; mi < 4; ++mi)
        #pragma unroll
        for (int nj = 0; nj < 4; ++nj)
          acc[mi][nj] = __builtin_amdgcn_mfma_f32_16x16x32_bf16(af[mi], bfv[nj], acc[mi][nj], 0, 0, 0);
    }
    __syncthreads();
  }
  int col = lane & 15, rbase = (lane >> 4) * 4;
  #pragma unroll
  for (int mi = 0; mi < 4; ++mi)
    #pragma unroll
    for (int nj = 0; nj < 4; ++nj)
      #pragma unroll
      for (int r = 0; r < 4; ++r)
        attn[((size_t)b * NN + bi + wr * 64 + mi * 16 + rbase + r) * NN
             + bj + wc * 64 + nj * 16 + col] = acc[mi][nj][r];
}

// ---------------- split-K kv (atomicAdd into zeroed buffer) ----------------
__global__ __launch_bounds__(256) void kv_kernel(
    const float* __restrict__ K3, const float* __restrict__ Vv,
    float* __restrict__ kvout) {
  int b = blockIdx.z, bp = blockIdx.x * 64;
  int j0base = blockIdx.y * (NN / 32);
  __shared__ float Ks[64][33], Vs[64][33];
  int t = threadIdx.x, tx = t & 15, ty = t >> 4;
  int lrow = t >> 2, ljc = (t & 3) * 8;
  float acc[4][4] = {};
  for (int j0 = j0base; j0 < j0base + NN / 32; j0 += 32) {
    float4 a0 = *(const float4*)(K3 + ((size_t)b * NM + bp + lrow) * NN + j0 + ljc);
    float4 a1 = *(const float4*)(K3 + ((size_t)b * NM + bp + lrow) * NN + j0 + ljc + 4);
    float4 v0 = *(const float4*)(Vv + ((size_t)b * NC + lrow) * NN + j0 + ljc);
    float4 v1 = *(const float4*)(Vv + ((size_t)b * NC + lrow) * NN + j0 + ljc + 4);
    Ks[lrow][ljc + 0] = a0.x; Ks[lrow][ljc + 1] = a0.y; Ks[lrow][ljc + 2] = a0.z; Ks[lrow][ljc + 3] = a0.w;
    Ks[lrow][ljc + 4] = a1.x; Ks[lrow][ljc + 5] = a1.y; Ks[lrow][ljc + 6] = a1.z; Ks[lrow][ljc + 7] = a1.w;
    Vs[lrow][ljc + 0] = v0.x; Vs[lrow][ljc + 1] = v0.y; Vs[lrow][ljc + 2] = v0.z; Vs[lrow][ljc + 3] = v0.w;
    Vs[lrow][ljc + 4] = v1.x; Vs[lrow][ljc + 5] = v1.y; Vs[lrow][ljc + 6] = v1.z; Vs[lrow][ljc + 7] = v1.w;
    __syncthreads();
    #pragma unroll
    for (int kk = 0; kk < 32; ++kk) {
      float av_[4], bv_[4];
      #pragma unroll
      for (int i = 0; i < 4; ++i) av_[i] = Ks[(ty << 2) + i][kk];
      #pragma unroll
      for (int j = 0; j < 4; ++j) bv_[j] = Vs[(tx << 2) + j][kk];
      #pragma unroll
      for (int i = 0; i < 4; ++i)
        #pragma unroll
        for (int j = 0; j < 4; ++j) acc[i][j] += av_[i] * bv_[j];
    }
    __syncthreads();
  }
  #pragma unroll
  for (int i = 0; i < 4; ++i)
    #pragma unroll
    for (int j = 0; j < 4; ++j)
      atomicAdd(&kvout[((size_t)b * NM + bp + (ty << 2) + i) * NC + (tx << 2) + j], acc[i][j]);
}

// ---------------- out = gamma*(A@kv) + x  (A in bf16) ----------------
__global__ __launch_bounds__(256) void out_kernel(
    const ushort* __restrict__ Abf, const float* __restrict__ kvm,
    const float* __restrict__ x, const float* __restrict__ gamma,
    float* __restrict__ outp) {
  __shared__ float As[32 * 256];
  int blk = blockIdx.x;
  int b = blk / (NN / 32), n0 = (blk % (NN / 32)) * 32;
  int t = threadIdx.x;
  for (int it = 0; it < 32; ++it)
    As[it * 256 + (t ^ (it & 31))] = bf2f(Abf[((size_t)b * NN + n0 + it) * NM + t]);
  __syncthreads();
  int tn = t & 31, cg0 = (t >> 5) * 8;
  float g = gamma[0];
  float acc[8] = {};
  for (int p = 0; p < NM; ++p) {
    float a = As[tn * 256 + (p ^ (tn & 31))];
    float4 kv0 = *(const float4*)(kvm + ((size_t)b * NM + p) * NC + cg0);
    float4 kv1 = *(const float4*)(kvm + ((size_t)b * NM + p) * NC + cg0 + 4);
    acc[0] += a * kv0.x; acc[1] += a * kv0.y; acc[2] += a * kv0.z; acc[3] += a * kv0.w;
    acc[4] += a * kv1.x; acc[5] += a * kv1.y; acc[6] += a * kv1.z; acc[7] += a * kv1.w;
  }
  #pragma unroll
  for (int qd = 0; qd < 8; ++qd) {
    int c = cg0 + qd;
    size_t idx = ((size_t)b * NC + c) * NN + n0 + tn;
    outp[idx] = g * acc[qd] + x[idx];
  }
}

extern "C" void kernel_launch(void* const* d_in, const int* in_sizes, int n_in,
                              void* d_out, int out_size, void* d_ws, size_t ws_size,
                              hipStream_t stream) {
  const float* x     = (const float*)d_in[0];
  const float* wq    = (const float*)d_in[1];
  const float* bq    = (const float*)d_in[2];
  const float* wk    = (const float*)d_in[3];
  const float* bk    = (const float*)d_in[4];
  const float* wv    = (const float*)d_in[5];
  const float* bv    = (const float*)d_in[6];
  const float* gamma = (const float*)d_in[7];
  float* outp = (float*)d_out;                       // [B][C][N]
  float* attn = outp + (size_t)NB * NC * NN;         // [B][N][N]
  float* w = (float*)d_ws;

  float* qw   = w;                 // [B][N][D]    65536
  float* kw   = qw + 65536;        // [B][N][D]    65536
  float* vw   = kw + 65536;        // [B][C][N]    524288
  float* qlw  = vw + 524288;       // [B][M][D]    4096
  float* klw  = qlw + 4096;        // [B][M][D]    4096
  float* k1w  = klw + 4096;        // [B][N][M]    2097152
  float* k2w  = k1w + 2097152;     // [B][M][M]    131072
  float* k3w  = k2w + 131072;      // [B][M][N]    2097152
  float* Abuf = k3w + 2097152;     // (region reused for Abf bf16)
  float* Va   = Abuf + 2097152;    // [B][M][M]    131072
  float* Vb   = Va + 131072;
  float* Zb   = Vb + 131072;
  float* T1   = Zb + 131072;
  float* T2   = T1 + 131072;
  float* kvw  = T2 + 131072;       // [B][M][C]    32768
  float* denw = kvw + 32768;       // [1]
  ushort* Abf = (ushort*)Abuf;     // [B][N][M] bf16 (4 MB of Abuf's 8 MB)
  ushort* k3T = (ushort*)k1w;      // [B][N][M] bf16 (k3^T; k1w dead after gemm_a)

  hipMemsetAsync(kvw, 0, (size_t)NB * NM * NC * sizeof(float), stream);
  qkv2_kernel<<<dim3(80, NN / 1024, NB), dim3(256), 0, stream>>>(
      x, wq, bq, wk, bk, wv, bv, qw, kw, vw);
  landmark_kernel<<<dim3(NB * NM * ND / 256), dim3(256), 0, stream>>>(qw, kw, qlw, klw);
  scores_softmax_m<<<dim3(NN / 4, NB), dim3(256), 0, stream>>>(qw, NN, klw, k1w);
  scores_softmax_m<<<dim3(NM / 4, NB), dim3(256), 0, stream>>>(qlw, NM, klw, k2w);
  scores_softmax_n<<<dim3(NM, NB), dim3(256), 0, stream>>>(qlw, kw, k3w);

  void* kargs[] = {(void*)&k2w, (void*)&Va, (void*)&Vb, (void*)&Zb,
                   (void*)&T1, (void*)&T2, (void*)&denw};
  hipLaunchCooperativeKernel((const void*)ns_kernel, dim3(128), dim3(256), kargs, 0, stream);

  gemm_a_kernel<<<dim3(NM / 64, NN / 64, NB), dim3(256), 0, stream>>>(k1w, Va, Abf);
  cvt_t_kernel<<<dim3(NN / 32, NM / 32, NB), dim3(256), 0, stream>>>(k3w, k3T);
  gemm_attn_mfma<<<dim3(NN / 128, NN / 128, NB), dim3(256), 0, stream>>>(Abf, k3T, attn);
  kv_kernel<<<dim3(NM / 64, 32, NB), dim3(256), 0, stream>>>(k3w, vw, kvw);
  out_kernel<<<dim3(NB * NN / 32), dim3(256), 0, stream>>>(Abf, kvw, x, gamma, outp);
}

// Round 4
// 369.234 us; speedup vs baseline: 2.8360x; 2.8360x over previous
//
#include <hip/hip_runtime.h>
#include <hip/hip_bf16.h>
#include <math.h>

#define NB 2        // batch
#define NC 64       // channels
#define ND 8        // head dim (C/8)
#define NN 4096     // tokens (T*W*H)
#define NM 256      // landmarks
#define NL 16       // N/M
#define SCALE 0.35355339059327373f  // 1/sqrt(8)

typedef __attribute__((ext_vector_type(4))) float f32x4;
typedef __attribute__((ext_vector_type(8))) short bf16x8;
typedef __attribute__((ext_vector_type(4))) int int4v;

__device__ inline ushort f2bf(float f) {
  __hip_bfloat16 h = __float2bfloat16(f);
  return *reinterpret_cast<ushort*>(&h);
}
__device__ inline float bf2f(ushort u) {
  return __uint_as_float(((unsigned int)u) << 16);
}

// ---------------- qkv projection, output-row parallel ----------------
__global__ __launch_bounds__(256) void qkv2_kernel(
    const float* __restrict__ x,
    const float* __restrict__ wq, const float* __restrict__ bq,
    const float* __restrict__ wk, const float* __restrict__ bk,
    const float* __restrict__ wv, const float* __restrict__ bv,
    float* __restrict__ q, float* __restrict__ k, float* __restrict__ v) {
  __shared__ float ws[NC];
  int o = blockIdx.x;            // 0..79: 0-7 q, 8-15 k, 16-79 v
  int b = blockIdx.z;
  int n0 = blockIdx.y * 1024;
  int t = threadIdx.x;
  const float* wrow;
  float bias;
  if (o < ND)            { wrow = wq + (size_t)o * NC;            bias = bq[o]; }
  else if (o < 2 * ND)   { wrow = wk + (size_t)(o - ND) * NC;     bias = bk[o - ND]; }
  else                   { wrow = wv + (size_t)(o - 2 * ND) * NC; bias = bv[o - 2 * ND]; }
  if (t < NC) ws[t] = wrow[t];
  __syncthreads();
  int n = n0 + t * 4;
  float4 acc = {bias, bias, bias, bias};
  #pragma unroll
  for (int c = 0; c < NC; ++c) {
    float wc = ws[c];
    float4 xv = *(const float4*)(x + ((size_t)b * NC + c) * NN + n);
    acc.x += wc * xv.x; acc.y += wc * xv.y; acc.z += wc * xv.z; acc.w += wc * xv.w;
  }
  if (o < ND) {
    float* qp = q + ((size_t)b * NN + n) * ND + o;
    qp[0] = acc.x; qp[8] = acc.y; qp[16] = acc.z; qp[24] = acc.w;
  } else if (o < 2 * ND) {
    float* kp = k + ((size_t)b * NN + n) * ND + (o - ND);
    kp[0] = acc.x; kp[8] = acc.y; kp[16] = acc.z; kp[24] = acc.w;
  } else {
    *(float4*)(v + ((size_t)b * NC + (o - 2 * ND)) * NN + n) = acc;
  }
}

// ---------------- landmarks ----------------
__global__ void landmark_kernel(const float* __restrict__ q, const float* __restrict__ k,
                                float* __restrict__ ql, float* __restrict__ kl) {
  int idx = blockIdx.x * 256 + threadIdx.x;
  int b = idx / (NM * ND), r = idx % (NM * ND), i = r / ND, o = r % ND;
  float sq = 0.f, sk = 0.f;
  for (int l = 0; l < NL; ++l) {
    size_t base = ((size_t)b * NN + i * NL + l) * ND + o;
    sq += q[base]; sk += k[base];
  }
  ql[idx] = sq * (1.0f / NL);
  kl[idx] = sk * (1.0f / NL);
}

// ---------------- softmax rows vs landmarks: bf16 output (k1) ----------------
__global__ __launch_bounds__(256) void scores_softmax_m_bf16(
    const float* __restrict__ Q, int R, const float* __restrict__ KL,
    ushort* __restrict__ out) {
  __shared__ float skl[NM][9];
  int b = blockIdx.y;
  int t = threadIdx.x;
  for (int i = t; i < NM * ND; i += 256) skl[i >> 3][i & 7] = KL[(size_t)b * NM * ND + i];
  __syncthreads();
  int wave = t >> 6, lane = t & 63;
  int r = blockIdx.x * 4 + wave;
  const float* qrow = Q + ((size_t)b * R + r) * ND;
  float qr[ND];
  #pragma unroll
  for (int dd = 0; dd < ND; ++dd) qr[dd] = qrow[dd];
  float sc[4];
  float lmax = -1e30f;
  #pragma unroll
  for (int s = 0; s < 4; ++s) {
    int j = lane + 64 * s;
    float a = 0.f;
    #pragma unroll
    for (int dd = 0; dd < ND; ++dd) a += qr[dd] * skl[j][dd];
    sc[s] = a * SCALE;
    lmax = fmaxf(lmax, sc[s]);
  }
  for (int off = 32; off; off >>= 1) lmax = fmaxf(lmax, __shfl_xor(lmax, off));
  float lsum = 0.f;
  #pragma unroll
  for (int s = 0; s < 4; ++s) { sc[s] = expf(sc[s] - lmax); lsum += sc[s]; }
  for (int off = 32; off; off >>= 1) lsum += __shfl_xor(lsum, off);
  float inv = 1.0f / lsum;
  #pragma unroll
  for (int s = 0; s < 4; ++s)
    out[((size_t)b * R + r) * NM + lane + 64 * s] = f2bf(sc[s] * inv);
}

// ---------------- softmax rows vs landmarks: fp32 output (k2) ----------------
__global__ __launch_bounds__(256) void scores_softmax_m_f32(
    const float* __restrict__ Q, int R, const float* __restrict__ KL,
    float* __restrict__ out) {
  __shared__ float skl[NM][9];
  int b = blockIdx.y;
  int t = threadIdx.x;
  for (int i = t; i < NM * ND; i += 256) skl[i >> 3][i & 7] = KL[(size_t)b * NM * ND + i];
  __syncthreads();
  int wave = t >> 6, lane = t & 63;
  int r = blockIdx.x * 4 + wave;
  const float* qrow = Q + ((size_t)b * R + r) * ND;
  float qr[ND];
  #pragma unroll
  for (int dd = 0; dd < ND; ++dd) qr[dd] = qrow[dd];
  float sc[4];
  float lmax = -1e30f;
  #pragma unroll
  for (int s = 0; s < 4; ++s) {
    int j = lane + 64 * s;
    float a = 0.f;
    #pragma unroll
    for (int dd = 0; dd < ND; ++dd) a += qr[dd] * skl[j][dd];
    sc[s] = a * SCALE;
    lmax = fmaxf(lmax, sc[s]);
  }
  for (int off = 32; off; off >>= 1) lmax = fmaxf(lmax, __shfl_xor(lmax, off));
  float lsum = 0.f;
  #pragma unroll
  for (int s = 0; s < 4; ++s) { sc[s] = expf(sc[s] - lmax); lsum += sc[s]; }
  for (int off = 32; off; off >>= 1) lsum += __shfl_xor(lsum, off);
  float inv = 1.0f / lsum;
  #pragma unroll
  for (int s = 0; s < 4; ++s) out[((size_t)b * R + r) * NM + lane + 64 * s] = sc[s] * inv;
}

// ---------------- k3 softmax (fp32 out) ----------------
__global__ __launch_bounds__(256) void scores_softmax_n(
    const float* __restrict__ QL, const float* __restrict__ Kt,
    float* __restrict__ out) {
  __shared__ float wred[4], wsum[4];
  int b = blockIdx.y, i = blockIdx.x;
  int t = threadIdx.x;
  float qr[ND];
  #pragma unroll
  for (int dd = 0; dd < ND; ++dd) qr[dd] = QL[((size_t)b * NM + i) * ND + dd];
  float sc[16];
  float lmax = -1e30f;
  #pragma unroll
  for (int s = 0; s < 16; ++s) {
    int n = t + 256 * s;
    const float* kp = Kt + ((size_t)b * NN + n) * ND;
    float a = 0.f;
    #pragma unroll
    for (int dd = 0; dd < ND; ++dd) a += qr[dd] * kp[dd];
    sc[s] = a * SCALE;
    lmax = fmaxf(lmax, sc[s]);
  }
  for (int off = 32; off; off >>= 1) lmax = fmaxf(lmax, __shfl_xor(lmax, off));
  if ((t & 63) == 0) wred[t >> 6] = lmax;
  __syncthreads();
  lmax = fmaxf(fmaxf(wred[0], wred[1]), fmaxf(wred[2], wred[3]));
  float lsum = 0.f;
  #pragma unroll
  for (int s = 0; s < 16; ++s) { sc[s] = expf(sc[s] - lmax); lsum += sc[s]; }
  for (int off = 32; off; off >>= 1) lsum += __shfl_xor(lsum, off);
  if ((t & 63) == 0) wsum[t >> 6] = lsum;
  __syncthreads();
  lsum = wsum[0] + wsum[1] + wsum[2] + wsum[3];
  float inv = 1.0f / lsum;
  #pragma unroll
  for (int s = 0; s < 16; ++s) out[((size_t)b * NM + i) * NN + t + 256 * s] = sc[s] * inv;
}

// ---------------- denom ----------------
__global__ void denom_kernel(const float* __restrict__ k2, float* __restrict__ denom) {
  __shared__ float redc[256], redr[256];
  int t = threadIdx.x;
  float mc = -1e30f, mr = -1e30f;
  for (int b = 0; b < NB; ++b) {
    float cs = 0.f, rs = 0.f;
    for (int i = 0; i < NM; ++i) {
      cs += k2[((size_t)b * NM + i) * NM + t];
      rs += k2[((size_t)b * NM + t) * NM + i];
    }
    mc = fmaxf(mc, cs); mr = fmaxf(mr, rs);
  }
  redc[t] = mc; redr[t] = mr;
  __syncthreads();
  for (int off = 128; off; off >>= 1) {
    if (t < off) {
      redc[t] = fmaxf(redc[t], redc[t + off]);
      redr[t] = fmaxf(redr[t], redr[t + off]);
    }
    __syncthreads();
  }
  if (t == 0) denom[0] = 1.0f / (redc[0] * redr[0]);
}

// ---------------- V0 = k2^T * invdenom ----------------
__global__ void vinit_kernel(const float* __restrict__ k2, const float* __restrict__ denom,
                             float* __restrict__ V) {
  int idx = blockIdx.x * 256 + threadIdx.x;
  int b = idx / (NM * NM), r = idx % (NM * NM), i = r / NM, j = r % NM;
  V[idx] = k2[((size_t)b * NM + j) * NM + i] * denom[0];
}

// ---------------- 32x32-tile batched GEMM for the NS chain ----------------
__global__ __launch_bounds__(256) void gemm_rk32(
    const float* __restrict__ A, const float* __restrict__ Bm,
    float* __restrict__ out, float s_a, float s_ab) {
  int b = blockIdx.z;
  int bi = blockIdx.y * 32, bj = blockIdx.x * 32;
  __shared__ float As[32][33], Bs[32][33];
  int t = threadIdx.x;
  int lr = t >> 3, lc = (t & 7) * 4;
  const float* Ab = A + (size_t)b * NM * NM;
  const float* Bb = Bm + (size_t)b * NM * NM;
  float acc[2][2] = {};
  int tx = t & 15, ty = t >> 4;
  for (int k0 = 0; k0 < NM; k0 += 32) {
    float4 av = *(const float4*)(Ab + (size_t)(bi + lr) * NM + k0 + lc);
    float4 bv = *(const float4*)(Bb + (size_t)(k0 + lr) * NM + bj + lc);
    As[lr][lc] = av.x; As[lr][lc + 1] = av.y; As[lr][lc + 2] = av.z; As[lr][lc + 3] = av.w;
    Bs[lr][lc] = bv.x; Bs[lr][lc + 1] = bv.y; Bs[lr][lc + 2] = bv.z; Bs[lr][lc + 3] = bv.w;
    __syncthreads();
    #pragma unroll
    for (int kk = 0; kk < 32; ++kk) {
      float a0 = As[ty * 2][kk], a1 = As[ty * 2 + 1][kk];
      float b0 = Bs[kk][tx * 2], b1 = Bs[kk][tx * 2 + 1];
      acc[0][0] += a0 * b0; acc[0][1] += a0 * b1;
      acc[1][0] += a1 * b0; acc[1][1] += a1 * b1;
    }
    __syncthreads();
  }
  #pragma unroll
  for (int i = 0; i < 2; ++i)
    #pragma unroll
    for (int j = 0; j < 2; ++j) {
      size_t o = ((size_t)b * NM + bi + ty * 2 + i) * NM + bj + tx * 2 + j;
      float r = s_ab * acc[i][j];
      if (s_a != 0.0f) r += s_a * A[o];
      out[o] = r;
    }
}

// ---------------- Vinv fp32 -> bf16 transposed: Vinvt[j][k] = Va[k][j] ----------------
__global__ __launch_bounds__(256) void cvt_vinv_kernel(const float* __restrict__ Va,
                                                       ushort* __restrict__ Vt) {
  int b = blockIdx.z;
  int n0 = blockIdx.x * 32, m0 = blockIdx.y * 32;
  __shared__ float tile[32][33];
  int t = threadIdx.x;
  int r = t >> 3, c4 = (t & 7) * 4;
  float4 v = *(const float4*)(Va + ((size_t)b * NM + m0 + r) * NM + n0 + c4);
  tile[c4][r] = v.x; tile[c4 + 1][r] = v.y; tile[c4 + 2][r] = v.z; tile[c4 + 3][r] = v.w;
  __syncthreads();
  ushort4 u;
  u.x = f2bf(tile[r][c4]);     u.y = f2bf(tile[r][c4 + 1]);
  u.z = f2bf(tile[r][c4 + 2]); u.w = f2bf(tile[r][c4 + 3]);
  *(ushort4*)(Vt + ((size_t)b * NM + n0 + r) * NM + m0 + c4) = u;
}

// ---------------- k3: [B][NM][NN] fp32 -> k3t: [B][NN][NM] bf16 ----------------
__global__ __launch_bounds__(256) void cvt_t_kernel(const float* __restrict__ k3,
                                                    ushort* __restrict__ k3t) {
  int b = blockIdx.z;
  int n0 = blockIdx.x * 32, m0 = blockIdx.y * 32;
  __shared__ float tile[32][33];
  int t = threadIdx.x;
  int r = t >> 3, c4 = (t & 7) * 4;
  float4 v = *(const float4*)(k3 + ((size_t)b * NM + m0 + r) * NN + n0 + c4);
  tile[c4][r] = v.x; tile[c4 + 1][r] = v.y; tile[c4 + 2][r] = v.z; tile[c4 + 3][r] = v.w;
  __syncthreads();
  ushort4 u;
  u.x = f2bf(tile[r][c4]);     u.y = f2bf(tile[r][c4 + 1]);
  u.z = f2bf(tile[r][c4 + 2]); u.w = f2bf(tile[r][c4 + 3]);
  *(ushort4*)(k3t + ((size_t)b * NN + n0 + r) * NM + m0 + c4) = u;
}

// ---------------- A = k1 @ Vinv via bf16 MFMA -> Abf bf16 ----------------
// k1bf: [B][NN][NM] bf16; Vt: [B][NM][NM] bf16 ([col j][k]); Abf: [B][NN][NM] bf16
__global__ __launch_bounds__(256) void gemm_a_mfma(
    const ushort* __restrict__ k1bf, const ushort* __restrict__ Vt,
    ushort* __restrict__ Abf) {
  int b = blockIdx.z;
  int bi = blockIdx.y * 128, bj = blockIdx.x * 128;
  __shared__ ushort As[128 * 64];
  __shared__ ushort Bs[128 * 64];
  int t = threadIdx.x;
  int wave = t >> 6, lane = t & 63;
  int wr = wave >> 1, wc = wave & 1;
  const ushort* Ab = k1bf + (size_t)b * NN * NM;
  const ushort* Bb = Vt + (size_t)b * NM * NM;
  f32x4 acc[4][4] = {};
  int srow = t >> 1;
  int sch0 = (t & 1) * 4;
  for (int k0 = 0; k0 < NM; k0 += 64) {
    #pragma unroll
    for (int cc = 0; cc < 4; ++cc) {
      int ch = sch0 + cc;
      int4v a = *(const int4v*)(Ab + (size_t)(bi + srow) * NM + k0 + ch * 8);
      int4v bv = *(const int4v*)(Bb + (size_t)(bj + srow) * NM + k0 + ch * 8);
      int sw = (ch * 16) ^ ((srow & 7) << 4);
      *(int4v*)((char*)As + srow * 128 + sw) = a;
      *(int4v*)((char*)Bs + srow * 128 + sw) = bv;
    }
    __syncthreads();
    #pragma unroll
    for (int kk = 0; kk < 2; ++kk) {
      int koff = kk * 64 + (lane >> 4) * 16;
      bf16x8 af[4], bfv[4];
      #pragma unroll
      for (int mi = 0; mi < 4; ++mi) {
        int row = wr * 64 + mi * 16 + (lane & 15);
        af[mi] = *(const bf16x8*)((const char*)As + row * 128 + (koff ^ ((row & 7) << 4)));
      }
      #pragma unroll
      for (int nj = 0; nj < 4; ++nj) {
        int row = wc * 64 + nj * 16 + (lane & 15);
        bfv[nj] = *(const bf16x8*)((const char*)Bs + row * 128 + (koff ^ ((row & 7) << 4)));
      }
      #pragma unroll
      for (int mi = 0; mi < 4; ++mi)
        #pragma unroll
        for (int nj = 0; nj < 4; ++nj)
          acc[mi][nj] = __builtin_amdgcn_mfma_f32_16x16x32_bf16(af[mi], bfv[nj], acc[mi][nj], 0, 0, 0);
    }
    __syncthreads();
  }
  int col = lane & 15, rbase = (lane >> 4) * 4;
  #pragma unroll
  for (int mi = 0; mi < 4; ++mi)
    #pragma unroll
    for (int nj = 0; nj < 4; ++nj)
      #pragma unroll
      for (int r = 0; r < 4; ++r)
        Abf[((size_t)b * NN + bi + wr * 64 + mi * 16 + rbase + r) * NM
            + bj + wc * 64 + nj * 16 + col] = f2bf(acc[mi][nj][r]);
}

// ---------------- attn = A @ k3 via bf16 MFMA, 128x128 tile, XCD swizzle ----------------
__global__ __launch_bounds__(256) void gemm_attn_mfma(
    const ushort* __restrict__ Abf, const ushort* __restrict__ K3T,
    float* __restrict__ attn) {
  // bijective XCD swizzle over all 2048 blocks (2048 % 8 == 0)
  int lin = blockIdx.z * 1024 + blockIdx.y * 32 + blockIdx.x;
  int swz = (lin & 7) * 256 + (lin >> 3);
  int b = swz >> 10;
  int rem = swz & 1023;
  int bi = (rem >> 5) * 128, bj = (rem & 31) * 128;
  __shared__ ushort As[128 * 64];
  __shared__ ushort Bs[128 * 64];
  int t = threadIdx.x;
  int wave = t >> 6, lane = t & 63;
  int wr = wave >> 1, wc = wave & 1;
  const ushort* Ab = Abf + (size_t)b * NN * NM;
  const ushort* Bb = K3T + (size_t)b * NN * NM;
  f32x4 acc[4][4] = {};
  int srow = t >> 1;
  int sch0 = (t & 1) * 4;
  for (int k0 = 0; k0 < NM; k0 += 64) {
    #pragma unroll
    for (int cc = 0; cc < 4; ++cc) {
      int ch = sch0 + cc;
      int4v a = *(const int4v*)(Ab + (size_t)(bi + srow) * NM + k0 + ch * 8);
      int4v bv = *(const int4v*)(Bb + (size_t)(bj + srow) * NM + k0 + ch * 8);
      int sw = (ch * 16) ^ ((srow & 7) << 4);
      *(int4v*)((char*)As + srow * 128 + sw) = a;
      *(int4v*)((char*)Bs + srow * 128 + sw) = bv;
    }
    __syncthreads();
    #pragma unroll
    for (int kk = 0; kk < 2; ++kk) {
      int koff = kk * 64 + (lane >> 4) * 16;
      bf16x8 af[4], bfv[4];
      #pragma unroll
      for (int mi = 0; mi < 4; ++mi) {
        int row = wr * 64 + mi * 16 + (lane & 15);
        af[mi] = *(const bf16x8*)((const char*)As + row * 128 + (koff ^ ((row & 7) << 4)));
      }
      #pragma unroll
      for (int nj = 0; nj < 4; ++nj) {
        int row = wc * 64 + nj * 16 + (lane & 15);
        bfv[nj] = *(const bf16x8*)((const char*)Bs + row * 128 + (koff ^ ((row & 7) << 4)));
      }
      #pragma unroll
      for (int mi = 0; mi < 4; ++mi)
        #pragma unroll
        for (int nj = 0; nj < 4; ++nj)
          acc[mi][nj] = __builtin_amdgcn_mfma_f32_16x16x32_bf16(af[mi], bfv[nj], acc[mi][nj], 0, 0, 0);
    }
    __syncthreads();
  }
  int col = lane & 15, rbase = (lane >> 4) * 4;
  #pragma unroll
  for (int mi = 0; mi < 4; ++mi)
    #pragma unroll
    for (int nj = 0; nj < 4; ++nj)
      #pragma unroll
      for (int r = 0; r < 4; ++r)
        attn[((size_t)b * NN + bi + wr * 64 + mi * 16 + rbase + r) * NN
             + bj + wc * 64 + nj * 16 + col] = acc[mi][nj][r];
}

// ---------------- split-K kv (atomicAdd into zeroed buffer) ----------------
__global__ __launch_bounds__(256) void kv_kernel(
    const float* __restrict__ K3, const float* __restrict__ Vv,
    float* __restrict__ kvout) {
  int b = blockIdx.z, bp = blockIdx.x * 64;
  int j0base = blockIdx.y * (NN / 32);
  __shared__ float Ks[64][33], Vs[64][33];
  int t = threadIdx.x, tx = t & 15, ty = t >> 4;
  int lrow = t >> 2, ljc = (t & 3) * 8;
  float acc[4][4] = {};
  for (int j0 = j0base; j0 < j0base + NN / 32; j0 += 32) {
    float4 a0 = *(const float4*)(K3 + ((size_t)b * NM + bp + lrow) * NN + j0 + ljc);
    float4 a1 = *(const float4*)(K3 + ((size_t)b * NM + bp + lrow) * NN + j0 + ljc + 4);
    float4 v0 = *(const float4*)(Vv + ((size_t)b * NC + lrow) * NN + j0 + ljc);
    float4 v1 = *(const float4*)(Vv + ((size_t)b * NC + lrow) * NN + j0 + ljc + 4);
    Ks[lrow][ljc + 0] = a0.x; Ks[lrow][ljc + 1] = a0.y; Ks[lrow][ljc + 2] = a0.z; Ks[lrow][ljc + 3] = a0.w;
    Ks[lrow][ljc + 4] = a1.x; Ks[lrow][ljc + 5] = a1.y; Ks[lrow][ljc + 6] = a1.z; Ks[lrow][ljc + 7] = a1.w;
    Vs[lrow][ljc + 0] = v0.x; Vs[lrow][ljc + 1] = v0.y; Vs[lrow][ljc + 2] = v0.z; Vs[lrow][ljc + 3] = v0.w;
    Vs[lrow][ljc + 4] = v1.x; Vs[lrow][ljc + 5] = v1.y; Vs[lrow][ljc + 6] = v1.z; Vs[lrow][ljc + 7] = v1.w;
    __syncthreads();
    #pragma unroll
    for (int kk = 0; kk < 32; ++kk) {
      float av_[4], bv_[4];
      #pragma unroll
      for (int i = 0; i < 4; ++i) av_[i] = Ks[(ty << 2) + i][kk];
      #pragma unroll
      for (int j = 0; j < 4; ++j) bv_[j] = Vs[(tx << 2) + j][kk];
      #pragma unroll
      for (int i = 0; i < 4; ++i)
        #pragma unroll
        for (int j = 0; j < 4; ++j) acc[i][j] += av_[i] * bv_[j];
    }
    __syncthreads();
  }
  #pragma unroll
  for (int i = 0; i < 4; ++i)
    #pragma unroll
    for (int j = 0; j < 4; ++j)
      atomicAdd(&kvout[((size_t)b * NM + bp + (ty << 2) + i) * NC + (tx << 2) + j], acc[i][j]);
}

// ---------------- out = gamma*(A@kv) + x  (A in bf16) ----------------
__global__ __launch_bounds__(256) void out_kernel(
    const ushort* __restrict__ Abf, const float* __restrict__ kvm,
    const float* __restrict__ x, const float* __restrict__ gamma,
    float* __restrict__ outp) {
  __shared__ float As[32 * 256];
  int blk = blockIdx.x;
  int b = blk / (NN / 32), n0 = (blk % (NN / 32)) * 32;
  int t = threadIdx.x;
  for (int it = 0; it < 32; ++it)
    As[it * 256 + (t ^ (it & 31))] = bf2f(Abf[((size_t)b * NN + n0 + it) * NM + t]);
  __syncthreads();
  int tn = t & 31, cg0 = (t >> 5) * 8;
  float g = gamma[0];
  float acc[8] = {};
  for (int p = 0; p < NM; ++p) {
    float a = As[tn * 256 + (p ^ (tn & 31))];
    float4 kv0 = *(const float4*)(kvm + ((size_t)b * NM + p) * NC + cg0);
    float4 kv1 = *(const float4*)(kvm + ((size_t)b * NM + p) * NC + cg0 + 4);
    acc[0] += a * kv0.x; acc[1] += a * kv0.y; acc[2] += a * kv0.z; acc[3] += a * kv0.w;
    acc[4] += a * kv1.x; acc[5] += a * kv1.y; acc[6] += a * kv1.z; acc[7] += a * kv1.w;
  }
  #pragma unroll
  for (int qd = 0; qd < 8; ++qd) {
    int c = cg0 + qd;
    size_t idx = ((size_t)b * NC + c) * NN + n0 + tn;
    outp[idx] = g * acc[qd] + x[idx];
  }
}

extern "C" void kernel_launch(void* const* d_in, const int* in_sizes, int n_in,
                              void* d_out, int out_size, void* d_ws, size_t ws_size,
                              hipStream_t stream) {
  const float* x     = (const float*)d_in[0];
  const float* wq    = (const float*)d_in[1];
  const float* bq    = (const float*)d_in[2];
  const float* wk    = (const float*)d_in[3];
  const float* bk    = (const float*)d_in[4];
  const float* wv    = (const float*)d_in[5];
  const float* bv    = (const float*)d_in[6];
  const float* gamma = (const float*)d_in[7];
  float* outp = (float*)d_out;                       // [B][C][N]
  float* attn = outp + (size_t)NB * NC * NN;         // [B][N][N]
  float* w = (float*)d_ws;

  float* qw   = w;                 // [B][N][D]    65536
  float* kw   = qw + 65536;        // [B][N][D]    65536
  float* vw   = kw + 65536;        // [B][C][N]    524288
  float* qlw  = vw + 524288;       // [B][M][D]    4096
  float* klw  = qlw + 4096;        // [B][M][D]    4096
  float* k1w  = klw + 4096;        // 8 MB region: k1bf (4MB) + k3T (4MB)
  float* k2w  = k1w + 2097152;     // [B][M][M]    131072
  float* k3w  = k2w + 131072;      // [B][M][N]    2097152
  float* Abuf = k3w + 2097152;     // 8 MB region: Abf bf16 (4MB)
  float* Va   = Abuf + 2097152;    // [B][M][M]    131072
  float* Vb   = Va + 131072;
  float* Zb   = Vb + 131072;
  float* T1   = Zb + 131072;
  float* T2   = T1 + 131072;
  float* kvw  = T2 + 131072;       // [B][M][C]    32768
  float* denw = kvw + 32768;       // [1]
  ushort* k1bf  = (ushort*)k1w;                 // [B][N][M] bf16
  ushort* k3T   = (ushort*)k1w + 2097152;       // [B][N][M] bf16 (k3^T)
  ushort* Abf   = (ushort*)Abuf;                // [B][N][M] bf16
  ushort* Vinvt = (ushort*)Zb;                  // [B][M][M] bf16 (Vinv^T), after NS

  hipMemsetAsync(kvw, 0, (size_t)NB * NM * NC * sizeof(float), stream);
  qkv2_kernel<<<dim3(80, NN / 1024, NB), dim3(256), 0, stream>>>(
      x, wq, bq, wk, bk, wv, bv, qw, kw, vw);
  landmark_kernel<<<dim3(NB * NM * ND / 256), dim3(256), 0, stream>>>(qw, kw, qlw, klw);
  scores_softmax_m_bf16<<<dim3(NN / 4, NB), dim3(256), 0, stream>>>(qw, NN, klw, k1bf);
  scores_softmax_m_f32<<<dim3(NM / 4, NB), dim3(256), 0, stream>>>(qlw, NM, klw, k2w);
  scores_softmax_n<<<dim3(NM, NB), dim3(256), 0, stream>>>(qlw, kw, k3w);
  denom_kernel<<<dim3(1), dim3(256), 0, stream>>>(k2w, denw);
  vinit_kernel<<<dim3(NB * NM * NM / 256), dim3(256), 0, stream>>>(k2w, denw, Va);

  float* Vc = Va; float* Vn = Vb;
  for (int it = 0; it < 6; ++it) {
    gemm_rk32<<<dim3(8, 8, NB), dim3(256), 0, stream>>>(k2w, Vc, Zb, 0.f, 1.f);     // Z = K@V
    gemm_rk32<<<dim3(8, 8, NB), dim3(256), 0, stream>>>(Zb, Zb, T1, 7.f, -1.f);     // T1 = 7Z - Z@Z
    gemm_rk32<<<dim3(8, 8, NB), dim3(256), 0, stream>>>(Zb, T1, T2, 15.f, -1.f);    // T2 = 15Z - Z@T1
    gemm_rk32<<<dim3(8, 8, NB), dim3(256), 0, stream>>>(Vc, T2, Vn, 3.25f, -0.25f); // V' = 3.25V - .25V@T2
    float* tmp = Vc; Vc = Vn; Vn = tmp;
  }
  // final Vinv in Va

  cvt_vinv_kernel<<<dim3(NM / 32, NM / 32, NB), dim3(256), 0, stream>>>(Va, Vinvt);
  cvt_t_kernel<<<dim3(NN / 32, NM / 32, NB), dim3(256), 0, stream>>>(k3w, k3T);
  gemm_a_mfma<<<dim3(NM / 128, NN / 128, NB), dim3(256), 0, stream>>>(k1bf, Vinvt, Abf);
  gemm_attn_mfma<<<dim3(NN / 128, NN / 128, NB), dim3(256), 0, stream>>>(Abf, k3T, attn);
  kv_kernel<<<dim3(NM / 64, 32, NB), dim3(256), 0, stream>>>(k3w, vw, kvw);
  out_kernel<<<dim3(NB * NN / 32), dim3(256), 0, stream>>>(Abf, kvw, x, gamma, outp);
}

// Round 5
// 303.211 us; speedup vs baseline: 3.4535x; 1.2177x over previous
//
#include <hip/hip_runtime.h>
#include <hip/hip_bf16.h>
#include <math.h>

#define NB 2        // batch
#define NC 64       // channels
#define ND 8        // head dim (C/8)
#define NN 4096     // tokens (T*W*H)
#define NM 256      // landmarks
#define NL 16       // N/M
#define SCALE 0.35355339059327373f  // 1/sqrt(8)

typedef __attribute__((ext_vector_type(4))) float f32x4;
typedef __attribute__((ext_vector_type(8))) short bf16x8;

__device__ inline ushort f2bf(float f) {
  __hip_bfloat16 h = __float2bfloat16(f);
  return *reinterpret_cast<ushort*>(&h);
}
__device__ inline float bf2f(ushort u) {
  return __uint_as_float(((unsigned int)u) << 16);
}

// async global->LDS, 16B per lane; LDS dest must be wave-linear (base + lane*16)
__device__ inline void gl_lds16(const void* g, void* l) {
  __builtin_amdgcn_global_load_lds(
      (const __attribute__((address_space(1))) unsigned int*)g,
      (__attribute__((address_space(3))) unsigned int*)l, 16, 0, 0);
}

// ---------------- qkv projection, output-row parallel ----------------
__global__ __launch_bounds__(256) void qkv2_kernel(
    const float* __restrict__ x,
    const float* __restrict__ wq, const float* __restrict__ bq,
    const float* __restrict__ wk, const float* __restrict__ bk,
    const float* __restrict__ wv, const float* __restrict__ bv,
    float* __restrict__ q, float* __restrict__ k, float* __restrict__ v) {
  __shared__ float ws[NC];
  int o = blockIdx.x;            // 0..79: 0-7 q, 8-15 k, 16-79 v
  int b = blockIdx.z;
  int n0 = blockIdx.y * 1024;
  int t = threadIdx.x;
  const float* wrow;
  float bias;
  if (o < ND)            { wrow = wq + (size_t)o * NC;            bias = bq[o]; }
  else if (o < 2 * ND)   { wrow = wk + (size_t)(o - ND) * NC;     bias = bk[o - ND]; }
  else                   { wrow = wv + (size_t)(o - 2 * ND) * NC; bias = bv[o - 2 * ND]; }
  if (t < NC) ws[t] = wrow[t];
  __syncthreads();
  int n = n0 + t * 4;
  float4 acc = {bias, bias, bias, bias};
  #pragma unroll
  for (int c = 0; c < NC; ++c) {
    float wc = ws[c];
    float4 xv = *(const float4*)(x + ((size_t)b * NC + c) * NN + n);
    acc.x += wc * xv.x; acc.y += wc * xv.y; acc.z += wc * xv.z; acc.w += wc * xv.w;
  }
  if (o < ND) {
    float* qp = q + ((size_t)b * NN + n) * ND + o;
    qp[0] = acc.x; qp[8] = acc.y; qp[16] = acc.z; qp[24] = acc.w;
  } else if (o < 2 * ND) {
    float* kp = k + ((size_t)b * NN + n) * ND + (o - ND);
    kp[0] = acc.x; kp[8] = acc.y; kp[16] = acc.z; kp[24] = acc.w;
  } else {
    *(float4*)(v + ((size_t)b * NC + (o - 2 * ND)) * NN + n) = acc;
  }
}

// ---------------- landmarks ----------------
__global__ void landmark_kernel(const float* __restrict__ q, const float* __restrict__ k,
                                float* __restrict__ ql, float* __restrict__ kl) {
  int idx = blockIdx.x * 256 + threadIdx.x;
  int b = idx / (NM * ND), r = idx % (NM * ND), i = r / ND, o = r % ND;
  float sq = 0.f, sk = 0.f;
  for (int l = 0; l < NL; ++l) {
    size_t base = ((size_t)b * NN + i * NL + l) * ND + o;
    sq += q[base]; sk += k[base];
  }
  ql[idx] = sq * (1.0f / NL);
  kl[idx] = sk * (1.0f / NL);
}

// ---------------- softmax rows vs landmarks: bf16 output (k1) ----------------
__global__ __launch_bounds__(256) void scores_softmax_m_bf16(
    const float* __restrict__ Q, int R, const float* __restrict__ KL,
    ushort* __restrict__ out) {
  __shared__ float skl[NM][9];
  int b = blockIdx.y;
  int t = threadIdx.x;
  for (int i = t; i < NM * ND; i += 256) skl[i >> 3][i & 7] = KL[(size_t)b * NM * ND + i];
  __syncthreads();
  int wave = t >> 6, lane = t & 63;
  int r = blockIdx.x * 4 + wave;
  const float* qrow = Q + ((size_t)b * R + r) * ND;
  float qr[ND];
  #pragma unroll
  for (int dd = 0; dd < ND; ++dd) qr[dd] = qrow[dd];
  float sc[4];
  float lmax = -1e30f;
  #pragma unroll
  for (int s = 0; s < 4; ++s) {
    int j = lane + 64 * s;
    float a = 0.f;
    #pragma unroll
    for (int dd = 0; dd < ND; ++dd) a += qr[dd] * skl[j][dd];
    sc[s] = a * SCALE;
    lmax = fmaxf(lmax, sc[s]);
  }
  for (int off = 32; off; off >>= 1) lmax = fmaxf(lmax, __shfl_xor(lmax, off));
  float lsum = 0.f;
  #pragma unroll
  for (int s = 0; s < 4; ++s) { sc[s] = expf(sc[s] - lmax); lsum += sc[s]; }
  for (int off = 32; off; off >>= 1) lsum += __shfl_xor(lsum, off);
  float inv = 1.0f / lsum;
  #pragma unroll
  for (int s = 0; s < 4; ++s)
    out[((size_t)b * R + r) * NM + lane + 64 * s] = f2bf(sc[s] * inv);
}

// ---------------- softmax rows vs landmarks: fp32 output (k2) ----------------
__global__ __launch_bounds__(256) void scores_softmax_m_f32(
    const float* __restrict__ Q, int R, const float* __restrict__ KL,
    float* __restrict__ out) {
  __shared__ float skl[NM][9];
  int b = blockIdx.y;
  int t = threadIdx.x;
  for (int i = t; i < NM * ND; i += 256) skl[i >> 3][i & 7] = KL[(size_t)b * NM * ND + i];
  __syncthreads();
  int wave = t >> 6, lane = t & 63;
  int r = blockIdx.x * 4 + wave;
  const float* qrow = Q + ((size_t)b * R + r) * ND;
  float qr[ND];
  #pragma unroll
  for (int dd = 0; dd < ND; ++dd) qr[dd] = qrow[dd];
  float sc[4];
  float lmax = -1e30f;
  #pragma unroll
  for (int s = 0; s < 4; ++s) {
    int j = lane + 64 * s;
    float a = 0.f;
    #pragma unroll
    for (int dd = 0; dd < ND; ++dd) a += qr[dd] * skl[j][dd];
    sc[s] = a * SCALE;
    lmax = fmaxf(lmax, sc[s]);
  }
  for (int off = 32; off; off >>= 1) lmax = fmaxf(lmax, __shfl_xor(lmax, off));
  float lsum = 0.f;
  #pragma unroll
  for (int s = 0; s < 4; ++s) { sc[s] = expf(sc[s] - lmax); lsum += sc[s]; }
  for (int off = 32; off; off >>= 1) lsum += __shfl_xor(lsum, off);
  float inv = 1.0f / lsum;
  #pragma unroll
  for (int s = 0; s < 4; ++s) out[((size_t)b * R + r) * NM + lane + 64 * s] = sc[s] * inv;
}

// ---------------- k3 softmax (fp32 out) ----------------
__global__ __launch_bounds__(256) void scores_softmax_n(
    const float* __restrict__ QL, const float* __restrict__ Kt,
    float* __restrict__ out) {
  __shared__ float wred[4], wsum[4];
  int b = blockIdx.y, i = blockIdx.x;
  int t = threadIdx.x;
  float qr[ND];
  #pragma unroll
  for (int dd = 0; dd < ND; ++dd) qr[dd] = QL[((size_t)b * NM + i) * ND + dd];
  float sc[16];
  float lmax = -1e30f;
  #pragma unroll
  for (int s = 0; s < 16; ++s) {
    int n = t + 256 * s;
    const float* kp = Kt + ((size_t)b * NN + n) * ND;
    float a = 0.f;
    #pragma unroll
    for (int dd = 0; dd < ND; ++dd) a += qr[dd] * kp[dd];
    sc[s] = a * SCALE;
    lmax = fmaxf(lmax, sc[s]);
  }
  for (int off = 32; off; off >>= 1) lmax = fmaxf(lmax, __shfl_xor(lmax, off));
  if ((t & 63) == 0) wred[t >> 6] = lmax;
  __syncthreads();
  lmax = fmaxf(fmaxf(wred[0], wred[1]), fmaxf(wred[2], wred[3]));
  float lsum = 0.f;
  #pragma unroll
  for (int s = 0; s < 16; ++s) { sc[s] = expf(sc[s] - lmax); lsum += sc[s]; }
  for (int off = 32; off; off >>= 1) lsum += __shfl_xor(lsum, off);
  if ((t & 63) == 0) wsum[t >> 6] = lsum;
  __syncthreads();
  lsum = wsum[0] + wsum[1] + wsum[2] + wsum[3];
  float inv = 1.0f / lsum;
  #pragma unroll
  for (int s = 0; s < 16; ++s) out[((size_t)b * NM + i) * NN + t + 256 * s] = sc[s] * inv;
}

// ---------------- denom: max column-sum per batch (row-sums of softmax == 1) ----------------
__global__ __launch_bounds__(256) void denom_kernel(const float* __restrict__ k2,
                                                    float* __restrict__ denw) {
  __shared__ float red[256];
  int b = blockIdx.x;
  int t = threadIdx.x;
  float cs = 0.f;
  for (int i = 0; i < NM; ++i) cs += k2[((size_t)b * NM + i) * NM + t];  // coalesced
  red[t] = cs;
  __syncthreads();
  for (int off = 128; off; off >>= 1) {
    if (t < off) red[t] = fmaxf(red[t], red[t + off]);
    __syncthreads();
  }
  if (t == 0) denw[b] = red[0];
}

// ---------------- V0 = k2^T * invdenom ----------------
__global__ void vinit_kernel(const float* __restrict__ k2, const float* __restrict__ denw,
                             float* __restrict__ V) {
  int idx = blockIdx.x * 256 + threadIdx.x;
  int b = idx / (NM * NM), r = idx % (NM * NM), i = r / NM, j = r % NM;
  float dval = 1.0f / fmaxf(denw[0], denw[1]);
  V[idx] = k2[((size_t)b * NM + j) * NM + i] * dval;
}

// ---------------- 32x32-tile batched GEMM, full-panel single-barrier staging ----------------
// out = s_a*A + s_ab*(A @ Bm);  A,Bm,out: [B][256][256]; grid (8,8,B)
__global__ __launch_bounds__(256) void gemm_rk32(
    const float* __restrict__ A, const float* __restrict__ Bm,
    float* __restrict__ out, float s_a, float s_ab) {
  int b = blockIdx.z;
  int bi = blockIdx.y * 32, bj = blockIdx.x * 32;
  __shared__ float As[32][260];   // [row][k], pad 260 for conflict-free + 16B-aligned rows
  __shared__ float Bs[256][36];   // [k][col], pad 36
  int t = threadIdx.x;
  const float* Ab = A + (size_t)b * NM * NM;
  const float* Bb = Bm + (size_t)b * NM * NM;
  #pragma unroll
  for (int q = 0; q < 8; ++q) {
    int s = q * 256 + t;
    int ar = s >> 6, ac = (s & 63) * 4;
    *(float4*)&As[ar][ac] = *(const float4*)(Ab + (size_t)(bi + ar) * NM + ac);
    int br = s >> 3, bc = (s & 7) * 4;
    *(float4*)&Bs[br][bc] = *(const float4*)(Bb + (size_t)br * NM + bj + bc);
  }
  __syncthreads();
  int tx = t & 15, ty = t >> 4;
  float acc[2][2] = {};
  #pragma unroll 8
  for (int kk = 0; kk < NM; ++kk) {
    float a0 = As[ty * 2][kk], a1 = As[ty * 2 + 1][kk];
    float b0 = Bs[kk][tx * 2], b1 = Bs[kk][tx * 2 + 1];
    acc[0][0] += a0 * b0; acc[0][1] += a0 * b1;
    acc[1][0] += a1 * b0; acc[1][1] += a1 * b1;
  }
  #pragma unroll
  for (int i = 0; i < 2; ++i)
    #pragma unroll
    for (int j = 0; j < 2; ++j) {
      size_t o = ((size_t)b * NM + bi + ty * 2 + i) * NM + bj + tx * 2 + j;
      float r = s_ab * acc[i][j];
      if (s_a != 0.0f) r += s_a * A[o];
      out[o] = r;
    }
}

// ---------------- Vinv fp32 -> bf16 transposed ----------------
__global__ __launch_bounds__(256) void cvt_vinv_kernel(const float* __restrict__ Va,
                                                       ushort* __restrict__ Vt) {
  int b = blockIdx.z;
  int n0 = blockIdx.x * 32, m0 = blockIdx.y * 32;
  __shared__ float tile[32][33];
  int t = threadIdx.x;
  int r = t >> 3, c4 = (t & 7) * 4;
  float4 v = *(const float4*)(Va + ((size_t)b * NM + m0 + r) * NM + n0 + c4);
  tile[c4][r] = v.x; tile[c4 + 1][r] = v.y; tile[c4 + 2][r] = v.z; tile[c4 + 3][r] = v.w;
  __syncthreads();
  ushort4 u;
  u.x = f2bf(tile[r][c4]);     u.y = f2bf(tile[r][c4 + 1]);
  u.z = f2bf(tile[r][c4 + 2]); u.w = f2bf(tile[r][c4 + 3]);
  *(ushort4*)(Vt + ((size_t)b * NM + n0 + r) * NM + m0 + c4) = u;
}

// ---------------- k3: [B][NM][NN] fp32 -> k3t: [B][NN][NM] bf16 ----------------
__global__ __launch_bounds__(256) void cvt_t_kernel(const float* __restrict__ k3,
                                                    ushort* __restrict__ k3t) {
  int b = blockIdx.z;
  int n0 = blockIdx.x * 32, m0 = blockIdx.y * 32;
  __shared__ float tile[32][33];
  int t = threadIdx.x;
  int r = t >> 3, c4 = (t & 7) * 4;
  float4 v = *(const float4*)(k3 + ((size_t)b * NM + m0 + r) * NN + n0 + c4);
  tile[c4][r] = v.x; tile[c4 + 1][r] = v.y; tile[c4 + 2][r] = v.z; tile[c4 + 3][r] = v.w;
  __syncthreads();
  ushort4 u;
  u.x = f2bf(tile[r][c4]);     u.y = f2bf(tile[r][c4 + 1]);
  u.z = f2bf(tile[r][c4 + 2]); u.w = f2bf(tile[r][c4 + 3]);
  *(ushort4*)(k3t + ((size_t)b * NN + n0 + r) * NM + m0 + c4) = u;
}

// ---------------- A = k1 @ Vinv via bf16 MFMA (global_load_lds staging) ----------------
__global__ __launch_bounds__(256) void gemm_a_mfma(
    const ushort* __restrict__ k1bf, const ushort* __restrict__ Vt,
    ushort* __restrict__ Abf) {
  int b = blockIdx.z;
  int bi = blockIdx.y * 128, bj = blockIdx.x * 128;
  __shared__ ushort As[128 * 64];
  __shared__ ushort Bs[128 * 64];
  int t = threadIdx.x;
  int wave = t >> 6, lane = t & 63;
  int wr = wave >> 1, wc = wave & 1;
  const ushort* Ab = k1bf + (size_t)b * NN * NM;
  const ushort* Bb = Vt + (size_t)b * NM * NM;
  f32x4 acc[4][4] = {};
  for (int k0 = 0; k0 < NM; k0 += 64) {
    // linear LDS dest + inverse-swizzled global source (m173 pattern)
    #pragma unroll
    for (int q = 0; q < 4; ++q) {
      int s = q * 256 + t;
      int r = s >> 3, c = s & 7;
      int cs = (c ^ (r & 7)) << 3;      // element offset of 16B chunk
      gl_lds16(Ab + (size_t)(bi + r) * NM + k0 + cs, As + (size_t)s * 8);
      gl_lds16(Bb + (size_t)(bj + r) * NM + k0 + cs, Bs + (size_t)s * 8);
    }
    __syncthreads();
    #pragma unroll
    for (int kk = 0; kk < 2; ++kk) {
      int koff = kk * 64 + (lane >> 4) * 16;
      bf16x8 af[4], bfv[4];
      #pragma unroll
      for (int mi = 0; mi < 4; ++mi) {
        int row = wr * 64 + mi * 16 + (lane & 15);
        af[mi] = *(const bf16x8*)((const char*)As + row * 128 + (koff ^ ((row & 7) << 4)));
      }
      #pragma unroll
      for (int nj = 0; nj < 4; ++nj) {
        int row = wc * 64 + nj * 16 + (lane & 15);
        bfv[nj] = *(const bf16x8*)((const char*)Bs + row * 128 + (koff ^ ((row & 7) << 4)));
      }
      #pragma unroll
      for (int mi = 0; mi < 4; ++mi)
        #pragma unroll
        for (int nj = 0; nj < 4; ++nj)
          acc[mi][nj] = __builtin_amdgcn_mfma_f32_16x16x32_bf16(af[mi], bfv[nj], acc[mi][nj], 0, 0, 0);
    }
    __syncthreads();
  }
  int col = lane & 15, rbase = (lane >> 4) * 4;
  #pragma unroll
  for (int mi = 0; mi < 4; ++mi)
    #pragma unroll
    for (int nj = 0; nj < 4; ++nj)
      #pragma unroll
      for (int r = 0; r < 4; ++r)
        Abf[((size_t)b * NN + bi + wr * 64 + mi * 16 + rbase + r) * NM
            + bj + wc * 64 + nj * 16 + col] = f2bf(acc[mi][nj][r]);
}

// ---------------- attn = A @ k3 via bf16 MFMA, 128x128 tile, XCD swizzle ----------------
__global__ __launch_bounds__(256) void gemm_attn_mfma(
    const ushort* __restrict__ Abf, const ushort* __restrict__ K3T,
    float* __restrict__ attn) {
  // bijective XCD swizzle over all 2048 blocks (2048 % 8 == 0)
  int lin = blockIdx.z * 1024 + blockIdx.y * 32 + blockIdx.x;
  int swz = (lin & 7) * 256 + (lin >> 3);
  int b = swz >> 10;
  int rem = swz & 1023;
  int bi = (rem >> 5) * 128, bj = (rem & 31) * 128;
  __shared__ ushort As[128 * 64];
  __shared__ ushort Bs[128 * 64];
  int t = threadIdx.x;
  int wave = t >> 6, lane = t & 63;
  int wr = wave >> 1, wc = wave & 1;
  const ushort* Ab = Abf + (size_t)b * NN * NM;
  const ushort* Bb = K3T + (size_t)b * NN * NM;
  f32x4 acc[4][4] = {};
  for (int k0 = 0; k0 < NM; k0 += 64) {
    #pragma unroll
    for (int q = 0; q < 4; ++q) {
      int s = q * 256 + t;
      int r = s >> 3, c = s & 7;
      int cs = (c ^ (r & 7)) << 3;
      gl_lds16(Ab + (size_t)(bi + r) * NM + k0 + cs, As + (size_t)s * 8);
      gl_lds16(Bb + (size_t)(bj + r) * NM + k0 + cs, Bs + (size_t)s * 8);
    }
    __syncthreads();
    #pragma unroll
    for (int kk = 0; kk < 2; ++kk) {
      int koff = kk * 64 + (lane >> 4) * 16;
      bf16x8 af[4], bfv[4];
      #pragma unroll
      for (int mi = 0; mi < 4; ++mi) {
        int row = wr * 64 + mi * 16 + (lane & 15);
        af[mi] = *(const bf16x8*)((const char*)As + row * 128 + (koff ^ ((row & 7) << 4)));
      }
      #pragma unroll
      for (int nj = 0; nj < 4; ++nj) {
        int row = wc * 64 + nj * 16 + (lane & 15);
        bfv[nj] = *(const bf16x8*)((const char*)Bs + row * 128 + (koff ^ ((row & 7) << 4)));
      }
      #pragma unroll
      for (int mi = 0; mi < 4; ++mi)
        #pragma unroll
        for (int nj = 0; nj < 4; ++nj)
          acc[mi][nj] = __builtin_amdgcn_mfma_f32_16x16x32_bf16(af[mi], bfv[nj], acc[mi][nj], 0, 0, 0);
    }
    __syncthreads();
  }
  int col = lane & 15, rbase = (lane >> 4) * 4;
  #pragma unroll
  for (int mi = 0; mi < 4; ++mi)
    #pragma unroll
    for (int nj = 0; nj < 4; ++nj)
      #pragma unroll
      for (int r = 0; r < 4; ++r)
        attn[((size_t)b * NN + bi + wr * 64 + mi * 16 + rbase + r) * NN
             + bj + wc * 64 + nj * 16 + col] = acc[mi][nj][r];
}

// ---------------- split-K kv (atomicAdd into zeroed buffer) ----------------
__global__ __launch_bounds__(256) void kv_kernel(
    const float* __restrict__ K3, const float* __restrict__ Vv,
    float* __restrict__ kvout) {
  int b = blockIdx.z, bp = blockIdx.x * 64;
  int j0base = blockIdx.y * (NN / 32);
  __shared__ float Ks[64][33], Vs[64][33];
  int t = threadIdx.x, tx = t & 15, ty = t >> 4;
  int lrow = t >> 2, ljc = (t & 3) * 8;
  float acc[4][4] = {};
  for (int j0 = j0base; j0 < j0base + NN / 32; j0 += 32) {
    float4 a0 = *(const float4*)(K3 + ((size_t)b * NM + bp + lrow) * NN + j0 + ljc);
    float4 a1 = *(const float4*)(K3 + ((size_t)b * NM + bp + lrow) * NN + j0 + ljc + 4);
    float4 v0 = *(const float4*)(Vv + ((size_t)b * NC + lrow) * NN + j0 + ljc);
    float4 v1 = *(const float4*)(Vv + ((size_t)b * NC + lrow) * NN + j0 + ljc + 4);
    Ks[lrow][ljc + 0] = a0.x; Ks[lrow][ljc + 1] = a0.y; Ks[lrow][ljc + 2] = a0.z; Ks[lrow][ljc + 3] = a0.w;
    Ks[lrow][ljc + 4] = a1.x; Ks[lrow][ljc + 5] = a1.y; Ks[lrow][ljc + 6] = a1.z; Ks[lrow][ljc + 7] = a1.w;
    Vs[lrow][ljc + 0] = v0.x; Vs[lrow][ljc + 1] = v0.y; Vs[lrow][ljc + 2] = v0.z; Vs[lrow][ljc + 3] = v0.w;
    Vs[lrow][ljc + 4] = v1.x; Vs[lrow][ljc + 5] = v1.y; Vs[lrow][ljc + 6] = v1.z; Vs[lrow][ljc + 7] = v1.w;
    __syncthreads();
    #pragma unroll
    for (int kk = 0; kk < 32; ++kk) {
      float av_[4], bv_[4];
      #pragma unroll
      for (int i = 0; i < 4; ++i) av_[i] = Ks[(ty << 2) + i][kk];
      #pragma unroll
      for (int j = 0; j < 4; ++j) bv_[j] = Vs[(tx << 2) + j][kk];
      #pragma unroll
      for (int i = 0; i < 4; ++i)
        #pragma unroll
        for (int j = 0; j < 4; ++j) acc[i][j] += av_[i] * bv_[j];
    }
    __syncthreads();
  }
  #pragma unroll
  for (int i = 0; i < 4; ++i)
    #pragma unroll
    for (int j = 0; j < 4; ++j)
      atomicAdd(&kvout[((size_t)b * NM + bp + (ty << 2) + i) * NC + (tx << 2) + j], acc[i][j]);
}

// ---------------- out = gamma*(A@kv) + x  (A in bf16) ----------------
__global__ __launch_bounds__(256) void out_kernel(
    const ushort* __restrict__ Abf, const float* __restrict__ kvm,
    const float* __restrict__ x, const float* __restrict__ gamma,
    float* __restrict__ outp) {
  __shared__ float As[32 * 256];
  int blk = blockIdx.x;
  int b = blk / (NN / 32), n0 = (blk % (NN / 32)) * 32;
  int t = threadIdx.x;
  for (int it = 0; it < 32; ++it)
    As[it * 256 + (t ^ (it & 31))] = bf2f(Abf[((size_t)b * NN + n0 + it) * NM + t]);
  __syncthreads();
  int tn = t & 31, cg0 = (t >> 5) * 8;
  float g = gamma[0];
  float acc[8] = {};
  for (int p = 0; p < NM; ++p) {
    float a = As[tn * 256 + (p ^ (tn & 31))];
    float4 kv0 = *(const float4*)(kvm + ((size_t)b * NM + p) * NC + cg0);
    float4 kv1 = *(const float4*)(kvm + ((size_t)b * NM + p) * NC + cg0 + 4);
    acc[0] += a * kv0.x; acc[1] += a * kv0.y; acc[2] += a * kv0.z; acc[3] += a * kv0.w;
    acc[4] += a * kv1.x; acc[5] += a * kv1.y; acc[6] += a * kv1.z; acc[7] += a * kv1.w;
  }
  #pragma unroll
  for (int qd = 0; qd < 8; ++qd) {
    int c = cg0 + qd;
    size_t idx = ((size_t)b * NC + c) * NN + n0 + tn;
    outp[idx] = g * acc[qd] + x[idx];
  }
}

extern "C" void kernel_launch(void* const* d_in, const int* in_sizes, int n_in,
                              void* d_out, int out_size, void* d_ws, size_t ws_size,
                              hipStream_t stream) {
  const float* x     = (const float*)d_in[0];
  const float* wq    = (const float*)d_in[1];
  const float* bq    = (const float*)d_in[2];
  const float* wk    = (const float*)d_in[3];
  const float* bk    = (const float*)d_in[4];
  const float* wv    = (const float*)d_in[5];
  const float* bv    = (const float*)d_in[6];
  const float* gamma = (const float*)d_in[7];
  float* outp = (float*)d_out;                       // [B][C][N]
  float* attn = outp + (size_t)NB * NC * NN;         // [B][N][N]
  float* w = (float*)d_ws;

  float* qw   = w;                 // [B][N][D]    65536
  float* kw   = qw + 65536;        // [B][N][D]    65536
  float* vw   = kw + 65536;        // [B][C][N]    524288
  float* qlw  = vw + 524288;       // [B][M][D]    4096
  float* klw  = qlw + 4096;        // [B][M][D]    4096
  float* k1w  = klw + 4096;        // 8 MB region: k1bf (4MB) + k3T (4MB)
  float* k2w  = k1w + 2097152;     // [B][M][M]    131072
  float* k3w  = k2w + 131072;      // [B][M][N]    2097152
  float* Abuf = k3w + 2097152;     // 8 MB region: Abf bf16 (4MB)
  float* Va   = Abuf + 2097152;    // [B][M][M]    131072
  float* Vb   = Va + 131072;
  float* Zb   = Vb + 131072;
  float* T1   = Zb + 131072;
  float* T2   = T1 + 131072;
  float* kvw  = T2 + 131072;       // [B][M][C]    32768
  float* denw = kvw + 32768;       // [2]
  ushort* k1bf  = (ushort*)k1w;                 // [B][N][M] bf16
  ushort* k3T   = (ushort*)k1w + 2097152;       // [B][N][M] bf16 (k3^T)
  ushort* Abf   = (ushort*)Abuf;                // [B][N][M] bf16
  ushort* Vinvt = (ushort*)Zb;                  // [B][M][M] bf16 (Vinv^T), after NS

  hipMemsetAsync(kvw, 0, (size_t)NB * NM * NC * sizeof(float), stream);
  qkv2_kernel<<<dim3(80, NN / 1024, NB), dim3(256), 0, stream>>>(
      x, wq, bq, wk, bk, wv, bv, qw, kw, vw);
  landmark_kernel<<<dim3(NB * NM * ND / 256), dim3(256), 0, stream>>>(qw, kw, qlw, klw);
  scores_softmax_m_bf16<<<dim3(NN / 4, NB), dim3(256), 0, stream>>>(qw, NN, klw, k1bf);
  scores_softmax_m_f32<<<dim3(NM / 4, NB), dim3(256), 0, stream>>>(qlw, NM, klw, k2w);
  scores_softmax_n<<<dim3(NM, NB), dim3(256), 0, stream>>>(qlw, kw, k3w);
  denom_kernel<<<dim3(NB), dim3(256), 0, stream>>>(k2w, denw);
  vinit_kernel<<<dim3(NB * NM * NM / 256), dim3(256), 0, stream>>>(k2w, denw, Va);

  float* Vc = Va; float* Vn = Vb;
  for (int it = 0; it < 6; ++it) {
    gemm_rk32<<<dim3(8, 8, NB), dim3(256), 0, stream>>>(k2w, Vc, Zb, 0.f, 1.f);     // Z = K@V
    gemm_rk32<<<dim3(8, 8, NB), dim3(256), 0, stream>>>(Zb, Zb, T1, 7.f, -1.f);     // T1 = 7Z - Z@Z
    gemm_rk32<<<dim3(8, 8, NB), dim3(256), 0, stream>>>(Zb, T1, T2, 15.f, -1.f);    // T2 = 15Z - Z@T1
    gemm_rk32<<<dim3(8, 8, NB), dim3(256), 0, stream>>>(Vc, T2, Vn, 3.25f, -0.25f); // V' = 3.25V - .25V@T2
    float* tmp = Vc; Vc = Vn; Vn = tmp;
  }
  // final Vinv in Va

  cvt_vinv_kernel<<<dim3(NM / 32, NM / 32, NB), dim3(256), 0, stream>>>(Va, Vinvt);
  cvt_t_kernel<<<dim3(NN / 32, NM / 32, NB), dim3(256), 0, stream>>>(k3w, k3T);
  gemm_a_mfma<<<dim3(NM / 128, NN / 128, NB), dim3(256), 0, stream>>>(k1bf, Vinvt, Abf);
  gemm_attn_mfma<<<dim3(NN / 128, NN / 128, NB), dim3(256), 0, stream>>>(Abf, k3T, attn);
  kv_kernel<<<dim3(NM / 64, 32, NB), dim3(256), 0, stream>>>(k3w, vw, kvw);
  out_kernel<<<dim3(NB * NN / 32), dim3(256), 0, stream>>>(Abf, kvw, x, gamma, outp);
}